// Round 6
// baseline (405.555 us; speedup 1.0000x reference)
//
#include <hip/hip_runtime.h>

// GroupedQueryAttention: B=4,S=2048,D=1024,H=16,HK=4,HD=64,G=4, fp32 in/out.
// R13: small-tile high-occupancy GEMMs.
//  - Evidence: four different schedules (R9/R10/R11/R12) all give gemm_qkv
//    ~102us; FETCH varied 200->70MB with no time change; all pipes <16% busy;
//    occupancy 10-29%. The invariant is TLP: <=12 waves/CU. m102's shape
//    curve (320 TF @1 blk/CU vs 833 @4 blk/CU) says waves/CU is the lever.
//  - Change: BM=128 -> BN=64 tiles (acc[4][2], ~110 VGPR), single-buffer
//    24KB LDS, plain 2-barrier loop. Grid: qkv 1024Q+256K+256V=1536 blocks
//    (6/CU work, ~4-5 resident = 16-20 waves/CU), gemm_o 1024 blocks.
//    XCD remap kept (m-groups pinned per XCD). Swizzles unchanged.
// prep and attn_k (101.5us, MfmaUtil 32%, 16 waves/CU) unchanged as controls.

typedef unsigned short u16;
typedef unsigned int   u32;
typedef __bf16 bf16x4 __attribute__((ext_vector_type(4)));
typedef __bf16 bf16x8 __attribute__((ext_vector_type(8)));
typedef float  f32x4  __attribute__((ext_vector_type(4)));

#define MFMA(a,b,c) __builtin_amdgcn_mfma_f32_16x16x32_bf16((a),(b),(c),0,0,0)

#define GLDS(g, l) __builtin_amdgcn_global_load_lds(                          \
    (const __attribute__((address_space(1))) void*)(g),                       \
    (__attribute__((address_space(3))) void*)(l), 16, 0, 0)

#if __has_builtin(__builtin_amdgcn_exp2f)
#define EXP2(x) __builtin_amdgcn_exp2f(x)
#else
#define EXP2(x) exp2f(x)
#endif

__device__ __forceinline__ u16 f2bf(float f){
    u32 u = __builtin_bit_cast(u32, f);
    u += 0x7fffu + ((u >> 16) & 1u);      // RNE
    return (u16)(u >> 16);
}
__device__ __forceinline__ u32 pk2(float a, float b){
#if __has_builtin(__builtin_amdgcn_cvt_pk_bf16_f32)
    auto r = __builtin_amdgcn_cvt_pk_bf16_f32(a, b);
    return __builtin_bit_cast(u32, r);
#else
    return (u32)f2bf(a) | ((u32)f2bf(b) << 16);
#endif
}
__device__ __forceinline__ bf16x8 ldfrag(const u16* p){   // 16B-aligned
    return *(const bf16x8*)p;
}
__device__ __forceinline__ bf16x8 ld2x64(const u16* p){   // 8B-aligned
    bf16x4 lo = *(const bf16x4*)p;
    bf16x4 hi = *(const bf16x4*)(p + 4);
    bf16x8 r;
    r[0]=lo[0]; r[1]=lo[1]; r[2]=lo[2]; r[3]=lo[3];
    r[4]=hi[0]; r[5]=hi[1]; r[6]=hi[2]; r[7]=hi[3];
    return r;
}

// ---------------- prep: 4 weight transposes W[K][N] f32 -> WT[N][K] bf16 ----
__global__ __launch_bounds__(256) void prep(const float* __restrict__ Wq,
                                            const float* __restrict__ Wk,
                                            const float* __restrict__ Wv,
                                            const float* __restrict__ Wo,
                                            u16* WqT, u16* WkT, u16* WvT, u16* WoT){
    const int tid = threadIdx.x, bid = blockIdx.x;
    __shared__ float T[32][33];
    const float* W; u16* WT; int N, i;
    if (bid < 1024)      { W = Wq; WT = WqT; N = 1024; i = bid; }
    else if (bid < 1280) { W = Wk; WT = WkT; N =  256; i = bid - 1024; }
    else if (bid < 1536) { W = Wv; WT = WvT; N =  256; i = bid - 1280; }
    else                 { W = Wo; WT = WoT; N = 1024; i = bid - 1536; }
    int kt = (i & 31) * 32, nt = (i >> 5) * 32;
    int r = tid >> 3, c = tid & 7;
    float4 vv = *(const float4*)(W + (size_t)(kt + r) * N + nt + c * 4);
    T[r][c*4+0] = vv.x; T[r][c*4+1] = vv.y; T[r][c*4+2] = vv.z; T[r][c*4+3] = vv.w;
    __syncthreads();
    u32 lo = pk2(T[c*4+0][r], T[c*4+1][r]);
    u32 hi = pk2(T[c*4+2][r], T[c*4+3][r]);
    *(uint2*)(WT + (size_t)(nt + r) * 1024 + kt + c * 4) = make_uint2(lo, hi);
}

// ---------------- GEMM body: 128x64 tile, single-buffer, 2 barriers/K-tile --
// 4 waves; each wave computes a 64x32 sub-tile (acc[4][2]). LDS: As 128x64,
// Bs 64x64 u16 = 24KB total. B via GLDS (pre-swizzled source, linear dest);
// ATYPE 0: A fp32, load->cvt_pk->XOR-swizzled ds_write in staging phase
//          (slot (c4>>1)^(r&7) <-> read slot (ks*4+quad)^(l15&7)).
// ATYPE 1: A bf16 via GLDS (same swizzle family).
// EPI 0: bf16 C[M,N] (*oscale), swapped operands -> packed uint2 stores
// EPI 1: bf16 Vt[(b*256+n)*2048+s], unswapped (s-consecutive packing)
// EPI 2: f32 C[M,N], swapped -> float4 stores
template<int ATYPE, int EPI>
__device__ __forceinline__ void gemm_body(const void* __restrict__ Ap,
                                          const u16* __restrict__ Bt,
                                          void* __restrict__ Cp,
                                          int N, int K, int m0, int n0,
                                          u16* As, u16* Bs, float oscale){
    const int tid  = threadIdx.x;
    const int wave = tid >> 6, lane = tid & 63;
    const int quad = lane >> 4, l15 = lane & 15;
    const int wm = wave >> 1, wn = wave & 1;      // wave -> 64r x 32c sub-tile
    const int srow = lane >> 3;                   // GLDS swizzled staging
    const int scol = ((lane & 7) ^ srow) * 8;
    const int swz  = l15 & 7;
    const int c4 = tid & 15, r0 = tid >> 4;       // ATYPE0 A-load coords

    f32x4 acc[4][2];
    #pragma unroll
    for (int i = 0; i < 4; ++i)
        #pragma unroll
        for (int j = 0; j < 2; ++j) acc[i][j] = (f32x4){0.f, 0.f, 0.f, 0.f};

    const int nkt = K >> 6;
    for (int kt = 0; kt < nkt; ++kt){
        if (kt) __syncthreads();                  // MFMA(kt-1) done with LDS
        if constexpr (ATYPE == 0){
            const float* A = (const float*)Ap;
            #pragma unroll
            for (int p = 0; p < 8; ++p){
                int r = r0 + p * 16;
                float4 v = *(const float4*)(A + (size_t)(m0 + r) * K + kt*64 + c4*4);
                *(uint2*)&As[r*64 + (((c4>>1) ^ (r&7))*8 + (c4&1)*4)] =
                    make_uint2(pk2(v.x, v.y), pk2(v.z, v.w));
            }
        } else {
            const u16* A = (const u16*)Ap;
            const u16* ga = A + (size_t)(m0 + wave*32 + srow) * K + kt*64 + scol;
            #pragma unroll
            for (int p = 0; p < 4; ++p)
                GLDS(ga + (size_t)(p*8) * K, As + (wave*32 + p*8) * 64);
        }
        {   // B tile: 64 rows x 64 cols, 16 rows per wave
            const u16* gb = Bt + (size_t)(n0 + wave*16 + srow) * K + kt*64 + scol;
            #pragma unroll
            for (int p = 0; p < 2; ++p)
                GLDS(gb + (size_t)(p*8) * K, Bs + (wave*16 + p*8) * 64);
        }
        __syncthreads();                          // tile kt resident
        #pragma unroll
        for (int ks = 0; ks < 2; ++ks){
            bf16x8 af[4], bfr[2];
            #pragma unroll
            for (int mt = 0; mt < 4; ++mt)
                af[mt] = ldfrag(&As[(wm*64 + mt*16 + l15) * 64 +
                                    (((ks*4 + quad) ^ swz) * 8)]);
            #pragma unroll
            for (int nt = 0; nt < 2; ++nt)
                bfr[nt] = ldfrag(&Bs[(wn*32 + nt*16 + l15) * 64 +
                                     (((ks*4 + quad) ^ swz) * 8)]);
            #pragma unroll
            for (int mt = 0; mt < 4; ++mt)
                #pragma unroll
                for (int nt = 0; nt < 2; ++nt){
                    if constexpr (EPI == 1)
                        acc[mt][nt] = MFMA(af[mt], bfr[nt], acc[mt][nt]);
                    else
                        acc[mt][nt] = MFMA(bfr[nt], af[mt], acc[mt][nt]);
                }
        }
    }
    #pragma unroll
    for (int mt = 0; mt < 4; ++mt){
        #pragma unroll
        for (int nt = 0; nt < 2; ++nt){
            if constexpr (EPI == 1){
                // unswapped: C row = quad*4+reg (s, 4 consecutive); col = l15
                int rowb = m0 + wm*64 + mt*16 + quad*4;
                int col  = n0 + wn*32 + nt*16 + l15;
                u16* C = (u16*)Cp;
                int bb = rowb >> 11, s = rowb & 2047;
                u32 lo = pk2(acc[mt][nt][0], acc[mt][nt][1]);
                u32 hi = pk2(acc[mt][nt][2], acc[mt][nt][3]);
                *(uint2*)(C + (size_t)(bb * 256 + col) * 2048 + s) = make_uint2(lo, hi);
            } else {
                // swapped: C row = A rows = l15; col = B rows = quad*4+reg
                int row  = m0 + wm*64 + mt*16 + l15;
                int colb = n0 + wn*32 + nt*16 + quad*4;
                if constexpr (EPI == 0){
                    u16* C = (u16*)Cp;
                    u32 lo = pk2(acc[mt][nt][0]*oscale, acc[mt][nt][1]*oscale);
                    u32 hi = pk2(acc[mt][nt][2]*oscale, acc[mt][nt][3]*oscale);
                    *(uint2*)(C + (size_t)row * N + colb) = make_uint2(lo, hi);
                } else {
                    float* C = (float*)Cp;
                    *(f32x4*)(C + (size_t)row * N + colb) = acc[mt][nt];
                }
            }
        }
    }
}

// fused Q+K+V projection: 1024 Q + 256 K + 256 V = 1536 blocks (6/CU work).
// XCD-aware remap (T1): all n-tiles of an m-tile share bid%8.
__global__ __launch_bounds__(256) void gemm_qkv(const float* q, const u16* WqT, u16* Qp,
                                                const float* k, const u16* WkT, u16* Kp,
                                                const float* v, const u16* WvT, u16* Vt,
                                                float qscale){
    __shared__ u16 As[128 * 64];
    __shared__ u16 Bs[64 * 64];
    int bid = blockIdx.x;
    if (bid < 1024){
        int x = bid & 7, s = bid >> 3;            // x = XCD (bid%8 heuristic)
        int m = x * 8 + (s >> 4), n = s & 15;     // 64 m-tiles x 16 n-tiles
        gemm_body<0,0>((const void*)q, WqT, (void*)Qp, 1024, 1024,
                       m * 128, n * 64, As, Bs, qscale);
    } else if (bid < 1280){
        int i = bid - 1024;                       // 1024%8==0: i%8 == bid%8
        int x = i & 7, s = i >> 3;
        int m = x * 8 + (s >> 2), n = s & 3;      // 64 m-tiles x 4 n-tiles
        gemm_body<0,0>((const void*)k, WkT, (void*)Kp, 256, 1024,
                       m * 128, n * 64, As, Bs, 1.0f);
    } else {
        int i = bid - 1280;                       // 1280%8==0
        int x = i & 7, s = i >> 3;
        int m = x * 8 + (s >> 2), n = s & 3;
        gemm_body<0,1>((const void*)v, WvT, (void*)Vt, 256, 1024,
                       m * 128, n * 64, As, Bs, 1.0f);
    }
}

__global__ __launch_bounds__(256) void gemm_o(const u16* AO, const u16* WoT,
                                              float* Out){
    __shared__ u16 As[128 * 64];
    __shared__ u16 Bs[64 * 64];
    int bid = blockIdx.x;                         // 1024 blocks (4/CU)
    int x = bid & 7, s = bid >> 3;
    int m = x * 8 + (s >> 4), n = s & 15;         // 64 m-tiles x 16 n-tiles
    gemm_body<1,2>((const void*)AO, WoT, (void*)Out, 1024, 1024,
                   m * 128, n * 64, As, Bs, 1.0f);
}

// ---------------- flash attention (R8 structure, unchanged) -----------------
// grid (8 qtiles, 16 heads, 4 batch) = 512 blocks = 2/CU (one flat phase),
// 512 threads = 8 waves, 32 q-rows/wave (256 q-rows/block), 16 waves/CU.
// S^T = K.Q^T (Q pre-scaled by 0.125*log2e), no-max exp2, row-sums via
// all-ones MFMA, O^T = V^T.P. Double-buffered GLDS K/V staging, one barrier
// per kv-tile. LDS 66.8 KB -> 2 blocks/CU. VGPR capped at 128.
__global__ __launch_bounds__(512, 4) void attn_k(const u16* __restrict__ Qp,
                                                 const u16* __restrict__ Kp,
                                                 const u16* __restrict__ Vt,
                                                 u16* __restrict__ AO){
    constexpr int S = 2048, Dm = 1024, NKV = 256, PST = 68;
    __shared__ u16 Kb[2][64 * 64];
    __shared__ u16 Vb[2][64 * 64];
    __shared__ u16 Ps[256 * PST];        // Q staging, then per-wave P rows
    const int tid = threadIdx.x, wave = tid >> 6, lane = tid & 63;
    const int quad = lane >> 4, l15 = lane & 15;
    const int h = blockIdx.y, b = blockIdx.z;
    const int hk = h >> 2, q0 = blockIdx.x * 256;
    u16* pw = Ps + wave * (32 * PST);    // wave's 32 P rows (== its q rows)

    const int srow = lane >> 3;                   // 0..7
    const int scol = ((lane & 7) ^ srow) * 8;     // swizzled source col
    const int swz  = l15 & 7;                     // row-dependent read XOR

    auto issue = [&](int t){
        int j0 = t * 64, bufi = t & 1;
        int r = wave * 8 + srow;                  // each wave stages 8 rows
        GLDS(Kp + (size_t)(b * S + j0 + r) * NKV + hk * 64 + scol,
             &Kb[bufi][wave * 8 * 64]);
        GLDS(Vt + (size_t)(b * NKV + hk * 64 + r) * S + j0 + scol,
             &Vb[bufi][wave * 8 * 64]);
    };

    issue(0);                            // start tile-0 loads immediately
    {   // stage Q tile (256 rows x 64) into Ps, stride PST
        int c8 = tid & 7, r0 = tid >> 3;          // r0: 0..63
        #pragma unroll
        for (int p = 0; p < 4; ++p){
            int r = r0 + p * 64;
            uint4 v = *(const uint4*)(Qp + (size_t)(b * S + q0 + r) * Dm + h * 64 + c8 * 8);
            *(uint2*)&Ps[r * PST + c8 * 8]     = make_uint2(v.x, v.y);
            *(uint2*)&Ps[r * PST + c8 * 8 + 4] = make_uint2(v.z, v.w);
        }
    }
    __syncthreads();                     // Q published (also drains tile-0 vm)
    bf16x8 qf[2][2];                     // [mt][ks]; wave's 32 q-rows
    #pragma unroll
    for (int mt = 0; mt < 2; ++mt)
        #pragma unroll
        for (int ks = 0; ks < 2; ++ks)
            qf[mt][ks] = ld2x64(&Ps[(wave*32 + mt*16 + l15) * PST + ks*32 + quad*8]);

    const u32 one2 = 0x3F803F80u;        // bf16 1.0 pair
    const bf16x8 ones = __builtin_bit_cast(bf16x8, make_uint4(one2, one2, one2, one2));

    f32x4 O[4][2];                       // [dt][mt]: O^T tiles (d x q)
    #pragma unroll
    for (int dt = 0; dt < 4; ++dt)
        #pragma unroll
        for (int mt = 0; mt < 2; ++mt) O[dt][mt] = (f32x4){0.f, 0.f, 0.f, 0.f};
    f32x4 sums[2];                       // ones-MFMA row-sum accs
    #pragma unroll
    for (int mt = 0; mt < 2; ++mt) sums[mt] = (f32x4){0.f, 0.f, 0.f, 0.f};

    for (int t = 0; t < 32; ++t){
        __syncthreads();                 // tile t resident; buf[(t+1)&1] free
        if (t < 31) issue(t + 1);        // async into other buffer
        const u16* Kt = Kb[t & 1];
        const u16* Vs = Vb[t & 1];
        // S^T = K(64kv x 64d) . Q^T(64d x 32q); ak transient per-ks (VGPR cap)
        f32x4 sf[2][4];                  // [mt][nt]
        #pragma unroll
        for (int mt = 0; mt < 2; ++mt)
            #pragma unroll
            for (int nt = 0; nt < 4; ++nt) sf[mt][nt] = (f32x4){0.f, 0.f, 0.f, 0.f};
        #pragma unroll
        for (int ks = 0; ks < 2; ++ks){
            bf16x8 ak[4];
            #pragma unroll
            for (int nt = 0; nt < 4; ++nt)
                ak[nt] = ldfrag(&Kt[(nt*16 + l15) * 64 + (((ks*4 + quad) ^ swz) * 8)]);
            #pragma unroll
            for (int mt = 0; mt < 2; ++mt)
                #pragma unroll
                for (int nt = 0; nt < 4; ++nt)
                    sf[mt][nt] = MFMA(ak[nt], qf[mt][ks], sf[mt][nt]);
        }
        // lane holds (kv = nt*16+quad*4+r, q = mt*16+l15): exp2, packed P
        #pragma unroll
        for (int mt = 0; mt < 2; ++mt)
            #pragma unroll
            for (int nt = 0; nt < 4; ++nt){
                float e0 = EXP2(sf[mt][nt][0]);
                float e1 = EXP2(sf[mt][nt][1]);
                float e2 = EXP2(sf[mt][nt][2]);
                float e3 = EXP2(sf[mt][nt][3]);
                *(uint2*)&pw[(mt*16 + l15) * PST + nt*16 + quad*4] =
                    make_uint2(pk2(e0, e1), pk2(e2, e3));
            }
        __threadfence_block();           // P LDS write->read order (wave-local)
        // O^T += V^T(64d x 64kv) . P(64kv x 32q); sums += ones . P
        #pragma unroll
        for (int ks = 0; ks < 2; ++ks){
            bf16x8 av[4], bp[2];
            #pragma unroll
            for (int dt = 0; dt < 4; ++dt)
                av[dt] = ldfrag(&Vs[(dt*16 + l15) * 64 + (((ks*4 + quad) ^ swz) * 8)]);
            #pragma unroll
            for (int mt = 0; mt < 2; ++mt)
                bp[mt] = ld2x64(&pw[(mt*16 + l15) * PST + ks*32 + quad*8]);
            #pragma unroll
            for (int mt = 0; mt < 2; ++mt)
                sums[mt] = MFMA(ones, bp[mt], sums[mt]);
            #pragma unroll
            for (int dt = 0; dt < 4; ++dt)
                #pragma unroll
                for (int mt = 0; mt < 2; ++mt)
                    O[dt][mt] = MFMA(av[dt], bp[mt], O[dt][mt]);
        }
    }
    // epilogue: every reg/quad of sums[mt] holds the row-sum for its q col
    #pragma unroll
    for (int mt = 0; mt < 2; ++mt){
        float inv = 1.0f / sums[mt][0];
        size_t row = (size_t)(b * S + q0 + wave*32 + mt*16 + l15);
        #pragma unroll
        for (int dt = 0; dt < 4; ++dt){
            u32 lo = pk2(O[dt][mt][0] * inv, O[dt][mt][1] * inv);
            u32 hi = pk2(O[dt][mt][2] * inv, O[dt][mt][3] * inv);
            *(uint2*)(AO + row * Dm + h * 64 + dt*16 + quad*4) = make_uint2(lo, hi);
        }
    }
}

extern "C" void kernel_launch(void* const* d_in, const int* in_sizes, int n_in,
                              void* d_out, int out_size, void* d_ws, size_t ws_size,
                              hipStream_t stream){
    const float* q  = (const float*)d_in[0];
    const float* k  = (const float*)d_in[1];
    const float* v  = (const float*)d_in[2];
    const float* Wq = (const float*)d_in[3];
    const float* Wk = (const float*)d_in[4];
    const float* Wv = (const float*)d_in[5];
    const float* Wo = (const float*)d_in[6];
    char* ws = (char*)d_ws;
    const size_t MB = 1u << 20;
    u16* WqT = (u16*)(ws);               // [1024][1024]  2 MiB
    u16* WkT = (u16*)(ws + 2*MB);        // [ 256][1024]  0.5
    u16* WvT = (u16*)(ws + 2*MB + 512*1024);
    u16* WoT = (u16*)(ws + 3*MB);        // 2 MiB
    u16* Qp  = (u16*)(ws + 5*MB);        // Q-proj      16 MiB
    u16* Kp  = (u16*)(ws + 21*MB);       // K-proj       4 MiB
    u16* Vt  = (u16*)(ws + 25*MB);       // V-proj^T     4 MiB
    u16* AO  = (u16*)(ws + 29*MB);       // attn out    16 MiB

    const float cexp = 0.125f * 1.44269504f;   // softmax scale * log2(e)

    prep<<<dim3(2560), 256, 0, stream>>>(Wq, Wk, Wv, Wo, WqT, WkT, WvT, WoT);
    gemm_qkv<<<dim3(1536), 256, 0, stream>>>(q, WqT, Qp, k, WkT, Kp,
                                             v, WvT, Vt, cexp);
    attn_k<<<dim3(8, 16, 4), 512, 0, stream>>>(Qp, Kp, Vt, AO);
    gemm_o<<<dim3(1024), 256, 0, stream>>>(AO, WoT, (float*)d_out);
}

// Round 7
// 301.662 us; speedup vs baseline: 1.3444x; 1.3444x over previous
//
#include <hip/hip_runtime.h>

// GroupedQueryAttention: B=4,S=2048,D=1024,H=16,HK=4,HD=64,G=4, fp32 in/out.
// R14: clone attn_k's proven config into the GEMMs.
//  - Evidence: attn_k (512thr, dbuf, ONE barrier/tile, GLDS, 16 waves/CU)
//    = MfmaUtil 32%. No GEMM round combined all of these: R9 had 16 waves
//    but 2 barriers (vmcnt0 drain mid-tile); R10/R12 had 1-barrier dbuf at
//    only 8 waves; R13 doubled staging redundancy (180us, falsified TLP-only).
//  - gemm_body: 512 thr, 8 waves, wave-tile 32x64 (acc[2][4]), 128x128 tile,
//    dbuf 64KB LDS -> 2 blocks/CU = 16 waves/CU. Per K-tile: barrier ->
//    issue t+1 loads (GLDS B + fp32 A->regs) -> MFMA(t) -> cvt+write A(t+1)
//    into idle buffer -> barrier. Loads get the whole MFMA phase to land
//    before the barrier's vmcnt(0) (attn mechanism). No inline asm.
//  - launch_bounds(512,4) caps VGPR 128 (est ~100, no spill - R11 lesson).
//    XCD remap kept (FETCH 200->70MB, R11). Swizzles unchanged (refcheck'd).
// prep and attn_k unchanged as controls.

typedef unsigned short u16;
typedef unsigned int   u32;
typedef __bf16 bf16x4 __attribute__((ext_vector_type(4)));
typedef __bf16 bf16x8 __attribute__((ext_vector_type(8)));
typedef float  f32x4  __attribute__((ext_vector_type(4)));

#define MFMA(a,b,c) __builtin_amdgcn_mfma_f32_16x16x32_bf16((a),(b),(c),0,0,0)

#define GLDS(g, l) __builtin_amdgcn_global_load_lds(                          \
    (const __attribute__((address_space(1))) void*)(g),                       \
    (__attribute__((address_space(3))) void*)(l), 16, 0, 0)

#if __has_builtin(__builtin_amdgcn_exp2f)
#define EXP2(x) __builtin_amdgcn_exp2f(x)
#else
#define EXP2(x) exp2f(x)
#endif

__device__ __forceinline__ u16 f2bf(float f){
    u32 u = __builtin_bit_cast(u32, f);
    u += 0x7fffu + ((u >> 16) & 1u);      // RNE
    return (u16)(u >> 16);
}
__device__ __forceinline__ u32 pk2(float a, float b){
#if __has_builtin(__builtin_amdgcn_cvt_pk_bf16_f32)
    auto r = __builtin_amdgcn_cvt_pk_bf16_f32(a, b);
    return __builtin_bit_cast(u32, r);
#else
    return (u32)f2bf(a) | ((u32)f2bf(b) << 16);
#endif
}
__device__ __forceinline__ bf16x8 ldfrag(const u16* p){   // 16B-aligned
    return *(const bf16x8*)p;
}
__device__ __forceinline__ bf16x8 ld2x64(const u16* p){   // 8B-aligned
    bf16x4 lo = *(const bf16x4*)p;
    bf16x4 hi = *(const bf16x4*)(p + 4);
    bf16x8 r;
    r[0]=lo[0]; r[1]=lo[1]; r[2]=lo[2]; r[3]=lo[3];
    r[4]=hi[0]; r[5]=hi[1]; r[6]=hi[2]; r[7]=hi[3];
    return r;
}

// ---------------- prep: 4 weight transposes W[K][N] f32 -> WT[N][K] bf16 ----
__global__ __launch_bounds__(256) void prep(const float* __restrict__ Wq,
                                            const float* __restrict__ Wk,
                                            const float* __restrict__ Wv,
                                            const float* __restrict__ Wo,
                                            u16* WqT, u16* WkT, u16* WvT, u16* WoT){
    const int tid = threadIdx.x, bid = blockIdx.x;
    __shared__ float T[32][33];
    const float* W; u16* WT; int N, i;
    if (bid < 1024)      { W = Wq; WT = WqT; N = 1024; i = bid; }
    else if (bid < 1280) { W = Wk; WT = WkT; N =  256; i = bid - 1024; }
    else if (bid < 1536) { W = Wv; WT = WvT; N =  256; i = bid - 1280; }
    else                 { W = Wo; WT = WoT; N = 1024; i = bid - 1536; }
    int kt = (i & 31) * 32, nt = (i >> 5) * 32;
    int r = tid >> 3, c = tid & 7;
    float4 vv = *(const float4*)(W + (size_t)(kt + r) * N + nt + c * 4);
    T[r][c*4+0] = vv.x; T[r][c*4+1] = vv.y; T[r][c*4+2] = vv.z; T[r][c*4+3] = vv.w;
    __syncthreads();
    u32 lo = pk2(T[c*4+0][r], T[c*4+1][r]);
    u32 hi = pk2(T[c*4+2][r], T[c*4+3][r]);
    *(uint2*)(WT + (size_t)(nt + r) * 1024 + kt + c * 4) = make_uint2(lo, hi);
}

// ---------------- GEMM body: attn-style 512-thr dbuf, 1 barrier/K-tile ------
// 8 waves, wave-tile 32(m) x 64(n): acc[2][4]. LDS: As/Bs each 2 x 128x64 u16
// (64KB total). Per tile: issue t+1 (GLDS B; A fp32->regs) right after the
// barrier; MFMA on current buffer; cvt+swizzled ds_write of A(t+1) into the
// idle buffer; ONE __syncthreads (its vmcnt0 drains loads that had the whole
// MFMA phase to land).
// ATYPE 0: A fp32 (reg-staged, cvt in writeA, XOR-swizzled ds_write:
//          slot (c4>>1)^(r&7) <-> read slot (ks*4+quad)^(l15&7))
// ATYPE 1: A bf16 via GLDS (pre-swizzled source, linear dest)
// EPI 0: bf16 C[M,N] (*oscale), swapped operands -> packed uint2 stores
// EPI 1: bf16 Vt[(b*256+n)*2048+s], unswapped (s-consecutive packing)
// EPI 2: f32 C[M,N], swapped -> float4 stores
template<int ATYPE, int EPI>
__device__ __forceinline__ void gemm_body(const void* __restrict__ Ap,
                                          const u16* __restrict__ Bt,
                                          void* __restrict__ Cp,
                                          int N, int K, int m0, int n0,
                                          u16* As, u16* Bs, float oscale){
    constexpr int TSZ = 128 * 64;
    const int tid  = threadIdx.x;
    const int wave = tid >> 6, lane = tid & 63;
    const int quad = lane >> 4, l15 = lane & 15;
    const int wm = wave >> 1, wn = wave & 1;      // 4x2 waves: 32r x 64c each
    const int srow = lane >> 3;                   // GLDS swizzled staging
    const int scol = ((lane & 7) ^ srow) * 8;
    const int swz  = l15 & 7;
    const int c4 = tid & 15, r0 = tid >> 4;       // ATYPE0 A coords (r0:0..31)

    f32x4 acc[2][4];
    #pragma unroll
    for (int i = 0; i < 2; ++i)
        #pragma unroll
        for (int j = 0; j < 4; ++j) acc[i][j] = (f32x4){0.f, 0.f, 0.f, 0.f};

    const int nkt = K >> 6;                       // 16
    float4 areg[4];                               // ATYPE0 in-flight A tile

    auto loadA = [&](int kt){                     // ATYPE0: global -> regs
        const float* A = (const float*)Ap;
        #pragma unroll
        for (int p = 0; p < 4; ++p)
            areg[p] = *(const float4*)(A + (size_t)(m0 + r0 + p*32) * K
                                         + kt*64 + c4*4);
    };
    auto writeA = [&](u16* dst){                  // cvt + swizzled ds_write
        #pragma unroll
        for (int p = 0; p < 4; ++p){
            int r = r0 + p*32;
            *(uint2*)&dst[r*64 + (((c4>>1) ^ (r&7))*8 + (c4&1)*4)] =
                make_uint2(pk2(areg[p].x, areg[p].y), pk2(areg[p].z, areg[p].w));
        }
    };
    auto issueAg = [&](int kt, u16* la){          // ATYPE1: GLDS A, 16 rows/wave
        const u16* A = (const u16*)Ap;
        const u16* ga = A + (size_t)(m0 + wave*16 + srow) * K + kt*64 + scol;
        #pragma unroll
        for (int p = 0; p < 2; ++p)
            GLDS(ga + (size_t)(p*8) * K, la + (wave*16 + p*8) * 64);
    };
    auto issueB = [&](int kt, u16* lb){           // GLDS B, 16 rows/wave
        const u16* gb = Bt + (size_t)(n0 + wave*16 + srow) * K + kt*64 + scol;
        #pragma unroll
        for (int p = 0; p < 2; ++p)
            GLDS(gb + (size_t)(p*8) * K, lb + (wave*16 + p*8) * 64);
    };
    auto mfmaPhase = [&](const u16* Asc, const u16* Bsc){
        #pragma unroll
        for (int ks = 0; ks < 2; ++ks){
            bf16x8 af[2], bfr[4];
            #pragma unroll
            for (int mt = 0; mt < 2; ++mt)
                af[mt] = ldfrag(&Asc[(wm*32 + mt*16 + l15) * 64 +
                                     (((ks*4 + quad) ^ swz) * 8)]);
            #pragma unroll
            for (int nt = 0; nt < 4; ++nt)
                bfr[nt] = ldfrag(&Bsc[(wn*64 + nt*16 + l15) * 64 +
                                      (((ks*4 + quad) ^ swz) * 8)]);
            #pragma unroll
            for (int mt = 0; mt < 2; ++mt)
                #pragma unroll
                for (int nt = 0; nt < 4; ++nt){
                    if constexpr (EPI == 1)
                        acc[mt][nt] = MFMA(af[mt], bfr[nt], acc[mt][nt]);
                    else
                        acc[mt][nt] = MFMA(bfr[nt], af[mt], acc[mt][nt]);
                }
        }
    };

    // ---- prologue: stage tile 0 into buffer 0 ----
    if constexpr (ATYPE == 0){
        loadA(0);
        issueB(0, Bs);
        writeA(As);                 // compiler inserts the areg waits
    } else {
        issueAg(0, As);
        issueB(0, Bs);
    }
    __syncthreads();                // tile 0 resident

    for (int t = 0; t < nkt; ++t){
        u16* Asc = As + (t & 1) * TSZ;
        u16* Bsc = Bs + (t & 1) * TSZ;
        u16* Aso = As + ((t & 1) ^ 1) * TSZ;
        u16* Bso = Bs + ((t & 1) ^ 1) * TSZ;
        const bool more = (t + 1 < nkt);
        if (more){                                // issue t+1 post-barrier
            if constexpr (ATYPE == 0) loadA(t + 1);
            else                      issueAg(t + 1, Aso);
            issueB(t + 1, Bso);
        }
        mfmaPhase(Asc, Bsc);                      // long phase hides loads
        if constexpr (ATYPE == 0){
            if (more) writeA(Aso);                // idle buffer; safe pre-bar
        }
        __syncthreads();                          // tile t+1 resident
    }

    #pragma unroll
    for (int mt = 0; mt < 2; ++mt){
        #pragma unroll
        for (int nt = 0; nt < 4; ++nt){
            if constexpr (EPI == 1){
                // unswapped: C row = quad*4+reg (s, 4 consecutive); col = l15
                int rowb = m0 + wm*32 + mt*16 + quad*4;
                int col  = n0 + wn*64 + nt*16 + l15;
                u16* C = (u16*)Cp;
                int bb = rowb >> 11, s = rowb & 2047;
                u32 lo = pk2(acc[mt][nt][0], acc[mt][nt][1]);
                u32 hi = pk2(acc[mt][nt][2], acc[mt][nt][3]);
                *(uint2*)(C + (size_t)(bb * 256 + col) * 2048 + s) = make_uint2(lo, hi);
            } else {
                // swapped: C row = A rows = l15; col = B rows = quad*4+reg
                int row  = m0 + wm*32 + mt*16 + l15;
                int colb = n0 + wn*64 + nt*16 + quad*4;
                if constexpr (EPI == 0){
                    u16* C = (u16*)Cp;
                    u32 lo = pk2(acc[mt][nt][0]*oscale, acc[mt][nt][1]*oscale);
                    u32 hi = pk2(acc[mt][nt][2]*oscale, acc[mt][nt][3]*oscale);
                    *(uint2*)(C + (size_t)row * N + colb) = make_uint2(lo, hi);
                } else {
                    float* C = (float*)Cp;
                    *(f32x4*)(C + (size_t)row * N + colb) = acc[mt][nt];
                }
            }
        }
    }
}

// fused Q+K+V projection: 512 Q + 128 K + 128 V = 768 blocks x 512 thr.
// XCD-aware remap (T1): all n-tiles of an m-tile share bid%8.
__global__ __launch_bounds__(512, 4) void gemm_qkv(const float* q, const u16* WqT, u16* Qp,
                                                   const float* k, const u16* WkT, u16* Kp,
                                                   const float* v, const u16* WvT, u16* Vt,
                                                   float qscale){
    __shared__ u16 As[2 * 128 * 64];
    __shared__ u16 Bs[2 * 128 * 64];
    int bid = blockIdx.x;
    if (bid < 512){
        int x = bid & 7, s = bid >> 3;            // x = XCD (bid%8 heuristic)
        int m = x * 8 + (s >> 3), n = s & 7;      // 64 m-tiles x 8 n-tiles
        gemm_body<0,0>((const void*)q, WqT, (void*)Qp, 1024, 1024,
                       m * 128, n * 128, As, Bs, qscale);
    } else if (bid < 640){
        int i = bid - 512;                        // 512%8==0: i%8 == bid%8
        int x = i & 7, s = i >> 3;
        int m = x * 8 + (s >> 1), n = s & 1;      // 64 m-tiles x 2 n-tiles
        gemm_body<0,0>((const void*)k, WkT, (void*)Kp, 256, 1024,
                       m * 128, n * 128, As, Bs, 1.0f);
    } else {
        int i = bid - 640;                        // 640%8==0
        int x = i & 7, s = i >> 3;
        int m = x * 8 + (s >> 1), n = s & 1;
        gemm_body<0,1>((const void*)v, WvT, (void*)Vt, 256, 1024,
                       m * 128, n * 128, As, Bs, 1.0f);
    }
}

__global__ __launch_bounds__(512, 4) void gemm_o(const u16* AO, const u16* WoT,
                                                 float* Out){
    __shared__ u16 As[2 * 128 * 64];
    __shared__ u16 Bs[2 * 128 * 64];
    int bid = blockIdx.x;                         // 512 blocks
    int x = bid & 7, s = bid >> 3;
    int m = x * 8 + (s >> 3), n = s & 7;          // 64 m-tiles x 8 n-tiles
    gemm_body<1,2>((const void*)AO, WoT, (void*)Out, 1024, 1024,
                   m * 128, n * 128, As, Bs, 1.0f);
}

// ---------------- flash attention (R8 structure, unchanged) -----------------
// grid (8 qtiles, 16 heads, 4 batch) = 512 blocks = 2/CU (one flat phase),
// 512 threads = 8 waves, 32 q-rows/wave (256 q-rows/block), 16 waves/CU.
// S^T = K.Q^T (Q pre-scaled by 0.125*log2e), no-max exp2, row-sums via
// all-ones MFMA, O^T = V^T.P. Double-buffered GLDS K/V staging, one barrier
// per kv-tile. LDS 66.8 KB -> 2 blocks/CU. VGPR capped at 128.
__global__ __launch_bounds__(512, 4) void attn_k(const u16* __restrict__ Qp,
                                                 const u16* __restrict__ Kp,
                                                 const u16* __restrict__ Vt,
                                                 u16* __restrict__ AO){
    constexpr int S = 2048, Dm = 1024, NKV = 256, PST = 68;
    __shared__ u16 Kb[2][64 * 64];
    __shared__ u16 Vb[2][64 * 64];
    __shared__ u16 Ps[256 * PST];        // Q staging, then per-wave P rows
    const int tid = threadIdx.x, wave = tid >> 6, lane = tid & 63;
    const int quad = lane >> 4, l15 = lane & 15;
    const int h = blockIdx.y, b = blockIdx.z;
    const int hk = h >> 2, q0 = blockIdx.x * 256;
    u16* pw = Ps + wave * (32 * PST);    // wave's 32 P rows (== its q rows)

    const int srow = lane >> 3;                   // 0..7
    const int scol = ((lane & 7) ^ srow) * 8;     // swizzled source col
    const int swz  = l15 & 7;                     // row-dependent read XOR

    auto issue = [&](int t){
        int j0 = t * 64, bufi = t & 1;
        int r = wave * 8 + srow;                  // each wave stages 8 rows
        GLDS(Kp + (size_t)(b * S + j0 + r) * NKV + hk * 64 + scol,
             &Kb[bufi][wave * 8 * 64]);
        GLDS(Vt + (size_t)(b * NKV + hk * 64 + r) * S + j0 + scol,
             &Vb[bufi][wave * 8 * 64]);
    };

    issue(0);                            // start tile-0 loads immediately
    {   // stage Q tile (256 rows x 64) into Ps, stride PST
        int c8 = tid & 7, r0 = tid >> 3;          // r0: 0..63
        #pragma unroll
        for (int p = 0; p < 4; ++p){
            int r = r0 + p * 64;
            uint4 v = *(const uint4*)(Qp + (size_t)(b * S + q0 + r) * Dm + h * 64 + c8 * 8);
            *(uint2*)&Ps[r * PST + c8 * 8]     = make_uint2(v.x, v.y);
            *(uint2*)&Ps[r * PST + c8 * 8 + 4] = make_uint2(v.z, v.w);
        }
    }
    __syncthreads();                     // Q published (also drains tile-0 vm)
    bf16x8 qf[2][2];                     // [mt][ks]; wave's 32 q-rows
    #pragma unroll
    for (int mt = 0; mt < 2; ++mt)
        #pragma unroll
        for (int ks = 0; ks < 2; ++ks)
            qf[mt][ks] = ld2x64(&Ps[(wave*32 + mt*16 + l15) * PST + ks*32 + quad*8]);

    const u32 one2 = 0x3F803F80u;        // bf16 1.0 pair
    const bf16x8 ones = __builtin_bit_cast(bf16x8, make_uint4(one2, one2, one2, one2));

    f32x4 O[4][2];                       // [dt][mt]: O^T tiles (d x q)
    #pragma unroll
    for (int dt = 0; dt < 4; ++dt)
        #pragma unroll
        for (int mt = 0; mt < 2; ++mt) O[dt][mt] = (f32x4){0.f, 0.f, 0.f, 0.f};
    f32x4 sums[2];                       // ones-MFMA row-sum accs
    #pragma unroll
    for (int mt = 0; mt < 2; ++mt) sums[mt] = (f32x4){0.f, 0.f, 0.f, 0.f};

    for (int t = 0; t < 32; ++t){
        __syncthreads();                 // tile t resident; buf[(t+1)&1] free
        if (t < 31) issue(t + 1);        // async into other buffer
        const u16* Kt = Kb[t & 1];
        const u16* Vs = Vb[t & 1];
        // S^T = K(64kv x 64d) . Q^T(64d x 32q); ak transient per-ks (VGPR cap)
        f32x4 sf[2][4];                  // [mt][nt]
        #pragma unroll
        for (int mt = 0; mt < 2; ++mt)
            #pragma unroll
            for (int nt = 0; nt < 4; ++nt) sf[mt][nt] = (f32x4){0.f, 0.f, 0.f, 0.f};
        #pragma unroll
        for (int ks = 0; ks < 2; ++ks){
            bf16x8 ak[4];
            #pragma unroll
            for (int nt = 0; nt < 4; ++nt)
                ak[nt] = ldfrag(&Kt[(nt*16 + l15) * 64 + (((ks*4 + quad) ^ swz) * 8)]);
            #pragma unroll
            for (int mt = 0; mt < 2; ++mt)
                #pragma unroll
                for (int nt = 0; nt < 4; ++nt)
                    sf[mt][nt] = MFMA(ak[nt], qf[mt][ks], sf[mt][nt]);
        }
        // lane holds (kv = nt*16+quad*4+r, q = mt*16+l15): exp2, packed P
        #pragma unroll
        for (int mt = 0; mt < 2; ++mt)
            #pragma unroll
            for (int nt = 0; nt < 4; ++nt){
                float e0 = EXP2(sf[mt][nt][0]);
                float e1 = EXP2(sf[mt][nt][1]);
                float e2 = EXP2(sf[mt][nt][2]);
                float e3 = EXP2(sf[mt][nt][3]);
                *(uint2*)&pw[(mt*16 + l15) * PST + nt*16 + quad*4] =
                    make_uint2(pk2(e0, e1), pk2(e2, e3));
            }
        __threadfence_block();           // P LDS write->read order (wave-local)
        // O^T += V^T(64d x 64kv) . P(64kv x 32q); sums += ones . P
        #pragma unroll
        for (int ks = 0; ks < 2; ++ks){
            bf16x8 av[4], bp[2];
            #pragma unroll
            for (int dt = 0; dt < 4; ++dt)
                av[dt] = ldfrag(&Vs[(dt*16 + l15) * 64 + (((ks*4 + quad) ^ swz) * 8)]);
            #pragma unroll
            for (int mt = 0; mt < 2; ++mt)
                bp[mt] = ld2x64(&pw[(mt*16 + l15) * PST + ks*32 + quad*8]);
            #pragma unroll
            for (int mt = 0; mt < 2; ++mt)
                sums[mt] = MFMA(ones, bp[mt], sums[mt]);
            #pragma unroll
            for (int dt = 0; dt < 4; ++dt)
                #pragma unroll
                for (int mt = 0; mt < 2; ++mt)
                    O[dt][mt] = MFMA(av[dt], bp[mt], O[dt][mt]);
        }
    }
    // epilogue: every reg/quad of sums[mt] holds the row-sum for its q col
    #pragma unroll
    for (int mt = 0; mt < 2; ++mt){
        float inv = 1.0f / sums[mt][0];
        size_t row = (size_t)(b * S + q0 + wave*32 + mt*16 + l15);
        #pragma unroll
        for (int dt = 0; dt < 4; ++dt){
            u32 lo = pk2(O[dt][mt][0] * inv, O[dt][mt][1] * inv);
            u32 hi = pk2(O[dt][mt][2] * inv, O[dt][mt][3] * inv);
            *(uint2*)(AO + row * Dm + h * 64 + dt*16 + quad*4) = make_uint2(lo, hi);
        }
    }
}

extern "C" void kernel_launch(void* const* d_in, const int* in_sizes, int n_in,
                              void* d_out, int out_size, void* d_ws, size_t ws_size,
                              hipStream_t stream){
    const float* q  = (const float*)d_in[0];
    const float* k  = (const float*)d_in[1];
    const float* v  = (const float*)d_in[2];
    const float* Wq = (const float*)d_in[3];
    const float* Wk = (const float*)d_in[4];
    const float* Wv = (const float*)d_in[5];
    const float* Wo = (const float*)d_in[6];
    char* ws = (char*)d_ws;
    const size_t MB = 1u << 20;
    u16* WqT = (u16*)(ws);               // [1024][1024]  2 MiB
    u16* WkT = (u16*)(ws + 2*MB);        // [ 256][1024]  0.5
    u16* WvT = (u16*)(ws + 2*MB + 512*1024);
    u16* WoT = (u16*)(ws + 3*MB);        // 2 MiB
    u16* Qp  = (u16*)(ws + 5*MB);        // Q-proj      16 MiB
    u16* Kp  = (u16*)(ws + 21*MB);       // K-proj       4 MiB
    u16* Vt  = (u16*)(ws + 25*MB);       // V-proj^T     4 MiB
    u16* AO  = (u16*)(ws + 29*MB);       // attn out    16 MiB

    const float cexp = 0.125f * 1.44269504f;   // softmax scale * log2(e)

    prep<<<dim3(2560), 256, 0, stream>>>(Wq, Wk, Wv, Wo, WqT, WkT, WvT, WoT);
    gemm_qkv<<<dim3(768), 512, 0, stream>>>(q, WqT, Qp, k, WkT, Kp,
                                            v, WvT, Vt, cexp);
    attn_k<<<dim3(8, 16, 4), 512, 0, stream>>>(Qp, Kp, Vt, AO);
    gemm_o<<<dim3(512), 512, 0, stream>>>(AO, WoT, (float*)d_out);
}